// Round 4
// baseline (2095.861 us; speedup 1.0000x reference)
//
#include <hip/hip_runtime.h>
#include <math.h>

#define BB 4
#define TT 4096
#define DD 768
#define SS 1024
#define S2 2048
#define KTOP 8
#define RWEIGHT 0.1f
#define TAU 2e-4f
#define AMB_CAP 1024

typedef __attribute__((ext_vector_type(8))) _Float16 f16x8;
typedef __attribute__((ext_vector_type(4))) float f32x4;
typedef _Float16 f16;

// ---------------------------------------------------------------------------
// build_slots: slots[0:S] = window-mean(4) of x (f32), slots[S:2S] = pm.
// ---------------------------------------------------------------------------
__global__ __launch_bounds__(256) void build_slots(
    const float* __restrict__ x, const float* __restrict__ pm,
    float* __restrict__ slots)
{
    int i = blockIdx.x * 256 + threadIdx.x;      // over S*D = 786432
    int s = i / DD;
    int d = i - s * DD;
    const float* xb = x + (size_t)(4 * s) * DD + d;
    slots[i] = 0.25f * (xb[0] + xb[DD] + xb[2 * DD] + xb[3 * DD]);
    slots[(size_t)SS * DD + i] = pm[i];
}

// ---------------------------------------------------------------------------
// transpose768: WT[j][i] = W[i][j], 768x768 f32.
// ---------------------------------------------------------------------------
__global__ __launch_bounds__(256) void transpose768(
    const float* __restrict__ W, float* __restrict__ WT)
{
    __shared__ float t[32][33];
    int bx = blockIdx.x * 32, by = blockIdx.y * 32;
    int lx = threadIdx.x & 31, ly = threadIdx.x >> 5;   // 32 x 8
#pragma unroll
    for (int r = 0; r < 32; r += 8)
        t[ly + r][lx] = W[(size_t)(bx + ly + r) * 768 + by + lx];
    __syncthreads();
#pragma unroll
    for (int r = 0; r < 32; r += 8)
        WT[(size_t)(by + ly + r) * 768 + bx + lx] = t[lx][ly + r];
}

__global__ void zero1(int* p) { *p = 0; }

// ---------------------------------------------------------------------------
// f16-split MFMA NT GEMM:  C[M,N] = alpha * A[M,768] @ B[N,768]^T + bscale*bias
// Split a = h + m (f16 each); products hh + hm + mh (mm ~2^-24 dropped).
// 128x128 tile, BK=32, 256 thr (4 waves 2x2, 64x64 each), 16x16x32 f16 MFMA.
// ---------------------------------------------------------------------------
__global__ __launch_bounds__(256) void mfma_nt_split(
    const float* __restrict__ A, const float* __restrict__ B,
    const float* __restrict__ bias, float* __restrict__ C,
    int N, float alpha, float bscale)
{
    __shared__ f16 Ah[128 * 32], Am[128 * 32], Bh[128 * 32], Bm[128 * 32];
    const int tid = threadIdx.x;
    const int lane = tid & 63;
    const int wc = (tid >> 6) & 1;
    const int wr = (tid >> 7) & 1;
    const size_t bm = (size_t)blockIdx.y * 128;
    const size_t bn = (size_t)blockIdx.x * 128;

    f32x4 acc[4][4];
#pragma unroll
    for (int i = 0; i < 4; ++i)
#pragma unroll
        for (int j = 0; j < 4; ++j) acc[i][j] = (f32x4){0.f, 0.f, 0.f, 0.f};

    const int srow = tid >> 1;
    const int skh = (tid & 1) * 16;
    const float* pa = A + (bm + srow) * 768 + skh;
    const float* pb = B + (bn + srow) * 768 + skh;
    const int c0 = skh >> 3;
    const int wo0 = srow * 32 + ((c0 ^ (srow & 3)) * 8);
    const int wo1 = srow * 32 + (((c0 + 1) ^ (srow & 3)) * 8);
    const int csw = (((lane >> 4) ^ (lane & 3)) * 8);

    for (int k0 = 0; k0 < 768; k0 += 32) {
        float4 a0 = *(const float4*)(pa + k0);
        float4 a1 = *(const float4*)(pa + k0 + 4);
        float4 a2 = *(const float4*)(pa + k0 + 8);
        float4 a3 = *(const float4*)(pa + k0 + 12);
        float4 b0 = *(const float4*)(pb + k0);
        float4 b1 = *(const float4*)(pb + k0 + 4);
        float4 b2 = *(const float4*)(pb + k0 + 8);
        float4 b3 = *(const float4*)(pb + k0 + 12);
        __syncthreads();
        {
            float av[16] = {a0.x, a0.y, a0.z, a0.w, a1.x, a1.y, a1.z, a1.w,
                            a2.x, a2.y, a2.z, a2.w, a3.x, a3.y, a3.z, a3.w};
            float bv[16] = {b0.x, b0.y, b0.z, b0.w, b1.x, b1.y, b1.z, b1.w,
                            b2.x, b2.y, b2.z, b2.w, b3.x, b3.y, b3.z, b3.w};
            f16x8 h, m;
#pragma unroll
            for (int j = 0; j < 8; ++j) {
                f16 hh = (f16)av[j]; h[j] = hh; m[j] = (f16)(av[j] - (float)hh);
            }
            *(f16x8*)&Ah[wo0] = h; *(f16x8*)&Am[wo0] = m;
#pragma unroll
            for (int j = 0; j < 8; ++j) {
                f16 hh = (f16)av[j + 8]; h[j] = hh; m[j] = (f16)(av[j + 8] - (float)hh);
            }
            *(f16x8*)&Ah[wo1] = h; *(f16x8*)&Am[wo1] = m;
#pragma unroll
            for (int j = 0; j < 8; ++j) {
                f16 hh = (f16)bv[j]; h[j] = hh; m[j] = (f16)(bv[j] - (float)hh);
            }
            *(f16x8*)&Bh[wo0] = h; *(f16x8*)&Bm[wo0] = m;
#pragma unroll
            for (int j = 0; j < 8; ++j) {
                f16 hh = (f16)bv[j + 8]; h[j] = hh; m[j] = (f16)(bv[j + 8] - (float)hh);
            }
            *(f16x8*)&Bh[wo1] = h; *(f16x8*)&Bm[wo1] = m;
        }
        __syncthreads();

        f16x8 fah[4], fam[4], fbh[4], fbm[4];
#pragma unroll
        for (int mi = 0; mi < 4; ++mi) {
            int off = (wr * 64 + mi * 16 + (lane & 15)) * 32 + csw;
            fah[mi] = *(const f16x8*)&Ah[off];
            fam[mi] = *(const f16x8*)&Am[off];
        }
#pragma unroll
        for (int ni = 0; ni < 4; ++ni) {
            int off = (wc * 64 + ni * 16 + (lane & 15)) * 32 + csw;
            fbh[ni] = *(const f16x8*)&Bh[off];
            fbm[ni] = *(const f16x8*)&Bm[off];
        }
#pragma unroll
        for (int mi = 0; mi < 4; ++mi)
#pragma unroll
            for (int ni = 0; ni < 4; ++ni) {
                acc[mi][ni] = __builtin_amdgcn_mfma_f32_16x16x32_f16(
                    fah[mi], fbh[ni], acc[mi][ni], 0, 0, 0);
                acc[mi][ni] = __builtin_amdgcn_mfma_f32_16x16x32_f16(
                    fah[mi], fbm[ni], acc[mi][ni], 0, 0, 0);
                acc[mi][ni] = __builtin_amdgcn_mfma_f32_16x16x32_f16(
                    fam[mi], fbh[ni], acc[mi][ni], 0, 0, 0);
            }
    }

    const int orow0 = wr * 64 + (lane >> 4) * 4;
    const int ocol0 = wc * 64 + (lane & 15);
#pragma unroll
    for (int mi = 0; mi < 4; ++mi)
#pragma unroll
        for (int ni = 0; ni < 4; ++ni) {
            size_t col = bn + ocol0 + ni * 16;
            float badd = bias ? bscale * bias[col] : 0.f;
            size_t rbase = bm + orow0 + mi * 16;
#pragma unroll
            for (int r = 0; r < 4; ++r)
                C[(rbase + r) * N + col] = alpha * acc[mi][ni][r] + badd;
        }
}

// ---------------------------------------------------------------------------
// wave top-NR of a 2048-score row: (value desc, index asc) = jax.lax.top_k.
// ---------------------------------------------------------------------------
template <int NR>
__device__ void wave_topk(const float* __restrict__ srow, int lane,
                          float* topv, int* topi)
{
    float vals[32];
#pragma unroll
    for (int i = 0; i < 32; ++i) vals[i] = srow[lane + (i << 6)];
#pragma unroll
    for (int r = 0; r < NR; ++r) {
        float bvv = -3.4e38f; int bii = 0x7fffffff;
#pragma unroll
        for (int i = 0; i < 32; ++i)
            if (vals[i] > bvv) { bvv = vals[i]; bii = lane + (i << 6); }
#pragma unroll
        for (int off = 32; off > 0; off >>= 1) {
            float ov = __shfl_xor(bvv, off);
            int   oi = __shfl_xor(bii, off);
            if (ov > bvv || (ov == bvv && oi < bii)) { bvv = ov; bii = oi; }
        }
        topv[r] = bvv; topi[r] = bii;
        if ((bii & 63) == lane) vals[bii >> 6] = -3.4e38f;
    }
}

// ---------------------------------------------------------------------------
// select_combine: one wave per row. top-9; gap test; softmax top-8; combine.
// ---------------------------------------------------------------------------
__global__ __launch_bounds__(256) void select_combine(
    const float* __restrict__ scores, const float* __restrict__ v,
    float* __restrict__ retrc,
    int* __restrict__ amb_count, int* __restrict__ amb_rows)
{
    const int lane = threadIdx.x & 63;
    const int wave = threadIdx.x >> 6;
    const int row = blockIdx.x * 4 + wave;

    float topv[9]; int topi[9];
    wave_topk<9>(scores + (size_t)row * S2, lane, topv, topi);

    if ((topv[7] - topv[8]) < TAU && lane == 0) {
        int idx = atomicAdd(amb_count, 1);
        if (idx < AMB_CAP) amb_rows[idx] = row;
    }

    float m = topv[0], w[KTOP], sum = 0.f;
#pragma unroll
    for (int r = 0; r < KTOP; ++r) { w[r] = expf(topv[r] - m); sum += w[r]; }
    float inv = 1.f / sum;

    const float4* v4 = (const float4*)v;
    float4* o4 = (float4*)(retrc + (size_t)row * DD);
#pragma unroll
    for (int c = 0; c < 3; ++c) {
        int col = c * 64 + lane;
        float4 accv = {0.f, 0.f, 0.f, 0.f};
#pragma unroll
        for (int r = 0; r < KTOP; ++r) {
            float4 vv = v4[(size_t)topi[r] * (DD / 4) + col];
            float wr = w[r] * inv;
            accv.x += wr * vv.x; accv.y += wr * vv.y;
            accv.z += wr * vv.z; accv.w += wr * vv.w;
        }
        o4[col] = accv;
    }
}

// ---------------------------------------------------------------------------
// fixup_fused: one block per ambiguous row.
//   q64 = f64(x_row @ Wq + bq)            via WqT, wave-parallel per output
//   u   = Wk @ q64                        wave-parallel per output
//   score_c = (slot_c . u + bk.q64)/sqrt  16 wave-parallel dots
//   f64 top-8 (val desc, idx asc), f64 softmax, combine v, overwrite row.
// ---------------------------------------------------------------------------
__global__ __launch_bounds__(256) void fixup_fused(
    const int* __restrict__ amb_count, const int* __restrict__ amb_rows,
    const float* __restrict__ xc,    // chunk x base
    const float* __restrict__ xb,    // batch x base (slot pooling)
    const float* __restrict__ pm,
    const float* __restrict__ WqT,   // [j][k]
    const float* __restrict__ Wk,    // [i][j]
    const float* __restrict__ bq, const float* __restrict__ bk,
    const float* __restrict__ scores, const float* __restrict__ v,
    float* __restrict__ retrc)
{
    int n = *amb_count; if (n > AMB_CAP) n = AMB_CAP;
    if ((int)blockIdx.x >= n) return;
    const int i = blockIdx.x;
    const int tid = threadIdx.x;
    const int lane = tid & 63;
    const int wave = tid >> 6;
    const int row = amb_rows[i];

    __shared__ float xs[768];
    __shared__ double q64[768];
    __shared__ double u[768];
    __shared__ double cs_s[16];
    __shared__ int cand_s[16];
    __shared__ double bkq_s;
    __shared__ float wsm[KTOP];
    __shared__ int seli[KTOP];

    for (int j = tid; j < 768; j += 256) xs[j] = xc[(size_t)row * 768 + j];
    __syncthreads();

    // q64
    for (int j = wave; j < 768; j += 4) {
        const float* wr = WqT + (size_t)j * 768;
        double p = 0.0;
#pragma unroll
        for (int t = 0; t < 12; ++t) {
            int k = lane + (t << 6);
            p = fma((double)xs[k], (double)wr[k], p);
        }
#pragma unroll
        for (int off = 32; off; off >>= 1) p += __shfl_xor(p, off);
        if (lane == 0) q64[j] = p + (double)bq[j];
    }
    if (wave == 0) {
        float tv[16]; int ti[16];
        wave_topk<16>(scores + (size_t)row * S2, lane, tv, ti);
        if (lane < 16) cand_s[lane] = ti[lane];
    }
    __syncthreads();

    // u = Wk @ q64
    for (int i2 = wave; i2 < 768; i2 += 4) {
        const float* wr = Wk + (size_t)i2 * 768;
        double p = 0.0;
#pragma unroll
        for (int t = 0; t < 12; ++t) {
            int j = lane + (t << 6);
            p = fma((double)wr[j], q64[j], p);
        }
#pragma unroll
        for (int off = 32; off; off >>= 1) p += __shfl_xor(p, off);
        if (lane == 0) u[i2] = p;
    }
    if (wave == 3) {
        double p = 0.0;
#pragma unroll
        for (int t = 0; t < 12; ++t) {
            int j = lane + (t << 6);
            p = fma((double)bk[j], q64[j], p);
        }
#pragma unroll
        for (int off = 32; off; off >>= 1) p += __shfl_xor(p, off);
        if (lane == 0) bkq_s = p;
    }
    __syncthreads();

    const double ISQ = 1.0 / sqrt((double)DD);
    for (int c = wave; c < 16; c += 4) {
        int s = cand_s[c];
        double p = 0.0;
        if (s < SS) {
            const float* xr = xb + (size_t)(4 * s) * 768;
#pragma unroll
            for (int t = 0; t < 12; ++t) {
                int j2 = lane + (t << 6);
                double sv = 0.25 * ((double)xr[j2] + (double)xr[j2 + 768] +
                                    (double)xr[j2 + 1536] + (double)xr[j2 + 2304]);
                p = fma(sv, u[j2], p);
            }
        } else {
            const float* pr = pm + (size_t)(s - SS) * 768;
#pragma unroll
            for (int t = 0; t < 12; ++t) {
                int j2 = lane + (t << 6);
                p = fma((double)pr[j2], u[j2], p);
            }
        }
#pragma unroll
        for (int off = 32; off; off >>= 1) p += __shfl_xor(p, off);
        if (lane == 0) cs_s[c] = (p + bkq_s) * ISQ;
    }
    __syncthreads();

    if (tid == 0) {
        double cs[16]; int ci[16];
        for (int c = 0; c < 16; ++c) { cs[c] = cs_s[c]; ci[c] = cand_s[c]; }
        unsigned used = 0;
        double sv[KTOP]; int sx[KTOP];
        for (int r = 0; r < KTOP; ++r) {
            int bi = -1;
            for (int c = 0; c < 16; ++c) {
                if (used & (1u << c)) continue;
                if (bi < 0 || cs[c] > cs[bi] ||
                    (cs[c] == cs[bi] && ci[c] < ci[bi])) bi = c;
            }
            used |= (1u << bi); sv[r] = cs[bi]; sx[r] = ci[bi];
        }
        double mx = sv[0], es[KTOP], ssum = 0.0;
        for (int r = 0; r < KTOP; ++r) { es[r] = exp(sv[r] - mx); ssum += es[r]; }
        for (int r = 0; r < KTOP; ++r) { wsm[r] = (float)(es[r] / ssum); seli[r] = sx[r]; }
    }
    __syncthreads();
    for (int j = tid; j < 768; j += 256) {
        float o = 0.f;
#pragma unroll
        for (int r = 0; r < KTOP; ++r) o += wsm[r] * v[(size_t)seli[r] * 768 + j];
        retrc[(size_t)row * 768 + j] = o;
    }
}

// ---------------------------------------------------------------------------
extern "C" void kernel_launch(void* const* d_in, const int* in_sizes, int n_in,
                              void* d_out, int out_size, void* d_ws, size_t ws_size,
                              hipStream_t stream)
{
    const float* x  = (const float*)d_in[0];
    const float* Wq = (const float*)d_in[1];
    const float* bq = (const float*)d_in[2];
    const float* Wk = (const float*)d_in[3];
    const float* bk = (const float*)d_in[4];
    const float* Wv = (const float*)d_in[5];
    const float* bv = (const float*)d_in[6];
    const float* Wp = (const float*)d_in[7];
    const float* bp = (const float*)d_in[8];
    const float* pm = (const float*)d_in[9];
    float* out = (float*)d_out;
    float* ws  = (float*)d_ws;

    const float inv_sqrt_d = (float)(1.0 / sqrt((double)DD));
    const size_t TD  = (size_t)TT * DD;
    const size_t SD2 = (size_t)S2 * DD;
    const size_t WSZ = (size_t)DD * DD;

    float* p = ws;
    float* WqT = p; p += WSZ;
    float* WkT = p; p += WSZ;
    float* WvT = p; p += WSZ;
    float* WpT = p; p += WSZ;
    float* slots = p; p += SD2;
    float* q32 = p; p += TD;
    float* k32 = p; p += SD2;
    float* v32 = p; p += SD2;
    float* retr = p; p += TD;
    int* ambc = (int*)p; p += 64;
    int* ambrows = (int*)p; p += AMB_CAP;
    float* scores = p;
    size_t used = (size_t)(p - ws);

    long tc = TT;
    while (tc > 512 && (used + (size_t)tc * S2) * 4 > ws_size) tc >>= 1;

    transpose768<<<dim3(24, 24), 256, 0, stream>>>(Wq, WqT);
    transpose768<<<dim3(24, 24), 256, 0, stream>>>(Wk, WkT);
    transpose768<<<dim3(24, 24), 256, 0, stream>>>(Wv, WvT);
    transpose768<<<dim3(24, 24), 256, 0, stream>>>(Wp, WpT);

    for (int b = 0; b < BB; ++b) {
        const float* xb = x + (size_t)b * TD;
        build_slots<<<(SS * DD) / 256, 256, 0, stream>>>(xb, pm, slots);
        mfma_nt_split<<<dim3(6, 32), 256, 0, stream>>>(
            xb, WqT, bq, q32, DD, 1.f, 1.f);
        mfma_nt_split<<<dim3(6, 16), 256, 0, stream>>>(
            slots, WkT, bk, k32, DD, 1.f, 1.f);
        mfma_nt_split<<<dim3(6, 16), 256, 0, stream>>>(
            slots, WvT, bv, v32, DD, 1.f, 1.f);

        for (long t0 = 0; t0 < TT; t0 += tc) {
            zero1<<<1, 1, 0, stream>>>(ambc);
            mfma_nt_split<<<dim3(16, tc / 128), 256, 0, stream>>>(
                q32 + (size_t)t0 * DD, k32, (const float*)nullptr, scores,
                S2, inv_sqrt_d, 0.f);
            select_combine<<<tc / 4, 256, 0, stream>>>(
                scores, v32, retr + (size_t)t0 * DD, ambc, ambrows);
            fixup_fused<<<AMB_CAP, 256, 0, stream>>>(
                ambc, ambrows, xb + (size_t)t0 * DD, xb, pm,
                WqT, Wk, bq, bk, scores, v32, retr + (size_t)t0 * DD);
        }

        mfma_nt_split<<<dim3(6, 32), 256, 0, stream>>>(
            retr, WpT, bp, out + (size_t)b * TD, DD, RWEIGHT, RWEIGHT);
    }
}

// Round 5
// 1382.623 us; speedup vs baseline: 1.5159x; 1.5159x over previous
//
#include <hip/hip_runtime.h>
#include <math.h>

#define BB 4
#define TT 4096
#define DD 768
#define SS 1024
#define S2 2048
#define KTOP 8
#define RWEIGHT 0.1f
#define TAU 2e-4f
#define AMB_CAP 1024

typedef __attribute__((ext_vector_type(8))) _Float16 f16x8;
typedef __attribute__((ext_vector_type(4))) float f32x4;
typedef _Float16 f16;

// ---------------------------------------------------------------------------
__global__ __launch_bounds__(256) void build_slots(
    const float* __restrict__ x, const float* __restrict__ pm,
    float* __restrict__ slots)
{
    int i = blockIdx.x * 256 + threadIdx.x;      // over S*D = 786432
    int s = i / DD;
    int d = i - s * DD;
    const float* xb = x + (size_t)(4 * s) * DD + d;
    slots[i] = 0.25f * (xb[0] + xb[DD] + xb[2 * DD] + xb[3 * DD]);
    slots[(size_t)SS * DD + i] = pm[i];
}

// ---------------------------------------------------------------------------
__global__ __launch_bounds__(256) void transpose768(
    const float* __restrict__ W, float* __restrict__ WT)
{
    __shared__ float t[32][33];
    int bx = blockIdx.x * 32, by = blockIdx.y * 32;
    int lx = threadIdx.x & 31, ly = threadIdx.x >> 5;   // 32 x 8
#pragma unroll
    for (int r = 0; r < 32; r += 8)
        t[ly + r][lx] = W[(size_t)(bx + ly + r) * 768 + by + lx];
    __syncthreads();
#pragma unroll
    for (int r = 0; r < 32; r += 8)
        WT[(size_t)(by + ly + r) * 768 + bx + lx] = t[lx][ly + r];
}

__global__ void zero1(int* p) { *p = 0; }

// ---------------------------------------------------------------------------
// f16-split MFMA NT GEMM:  C[M,N] = alpha * A[M,768] @ B[N,768]^T + bscale*bias
// ---------------------------------------------------------------------------
__global__ __launch_bounds__(256) void mfma_nt_split(
    const float* __restrict__ A, const float* __restrict__ B,
    const float* __restrict__ bias, float* __restrict__ C,
    int N, float alpha, float bscale)
{
    __shared__ f16 Ah[128 * 32], Am[128 * 32], Bh[128 * 32], Bm[128 * 32];
    const int tid = threadIdx.x;
    const int lane = tid & 63;
    const int wc = (tid >> 6) & 1;
    const int wr = (tid >> 7) & 1;
    const size_t bm = (size_t)blockIdx.y * 128;
    const size_t bn = (size_t)blockIdx.x * 128;

    f32x4 acc[4][4];
#pragma unroll
    for (int i = 0; i < 4; ++i)
#pragma unroll
        for (int j = 0; j < 4; ++j) acc[i][j] = (f32x4){0.f, 0.f, 0.f, 0.f};

    const int srow = tid >> 1;
    const int skh = (tid & 1) * 16;
    const float* pa = A + (bm + srow) * 768 + skh;
    const float* pb = B + (bn + srow) * 768 + skh;
    const int c0 = skh >> 3;
    const int wo0 = srow * 32 + ((c0 ^ (srow & 3)) * 8);
    const int wo1 = srow * 32 + (((c0 + 1) ^ (srow & 3)) * 8);
    const int csw = (((lane >> 4) ^ (lane & 3)) * 8);

    for (int k0 = 0; k0 < 768; k0 += 32) {
        float4 a0 = *(const float4*)(pa + k0);
        float4 a1 = *(const float4*)(pa + k0 + 4);
        float4 a2 = *(const float4*)(pa + k0 + 8);
        float4 a3 = *(const float4*)(pa + k0 + 12);
        float4 b0 = *(const float4*)(pb + k0);
        float4 b1 = *(const float4*)(pb + k0 + 4);
        float4 b2 = *(const float4*)(pb + k0 + 8);
        float4 b3 = *(const float4*)(pb + k0 + 12);
        __syncthreads();
        {
            float av[16] = {a0.x, a0.y, a0.z, a0.w, a1.x, a1.y, a1.z, a1.w,
                            a2.x, a2.y, a2.z, a2.w, a3.x, a3.y, a3.z, a3.w};
            float bv[16] = {b0.x, b0.y, b0.z, b0.w, b1.x, b1.y, b1.z, b1.w,
                            b2.x, b2.y, b2.z, b2.w, b3.x, b3.y, b3.z, b3.w};
            f16x8 h, m;
#pragma unroll
            for (int j = 0; j < 8; ++j) {
                f16 hh = (f16)av[j]; h[j] = hh; m[j] = (f16)(av[j] - (float)hh);
            }
            *(f16x8*)&Ah[wo0] = h; *(f16x8*)&Am[wo0] = m;
#pragma unroll
            for (int j = 0; j < 8; ++j) {
                f16 hh = (f16)av[j + 8]; h[j] = hh; m[j] = (f16)(av[j + 8] - (float)hh);
            }
            *(f16x8*)&Ah[wo1] = h; *(f16x8*)&Am[wo1] = m;
#pragma unroll
            for (int j = 0; j < 8; ++j) {
                f16 hh = (f16)bv[j]; h[j] = hh; m[j] = (f16)(bv[j] - (float)hh);
            }
            *(f16x8*)&Bh[wo0] = h; *(f16x8*)&Bm[wo0] = m;
#pragma unroll
            for (int j = 0; j < 8; ++j) {
                f16 hh = (f16)bv[j + 8]; h[j] = hh; m[j] = (f16)(bv[j + 8] - (float)hh);
            }
            *(f16x8*)&Bh[wo1] = h; *(f16x8*)&Bm[wo1] = m;
        }
        __syncthreads();

        f16x8 fah[4], fam[4], fbh[4], fbm[4];
#pragma unroll
        for (int mi = 0; mi < 4; ++mi) {
            int off = (wr * 64 + mi * 16 + (lane & 15)) * 32 + csw;
            fah[mi] = *(const f16x8*)&Ah[off];
            fam[mi] = *(const f16x8*)&Am[off];
        }
#pragma unroll
        for (int ni = 0; ni < 4; ++ni) {
            int off = (wc * 64 + ni * 16 + (lane & 15)) * 32 + csw;
            fbh[ni] = *(const f16x8*)&Bh[off];
            fbm[ni] = *(const f16x8*)&Bm[off];
        }
#pragma unroll
        for (int mi = 0; mi < 4; ++mi)
#pragma unroll
            for (int ni = 0; ni < 4; ++ni) {
                acc[mi][ni] = __builtin_amdgcn_mfma_f32_16x16x32_f16(
                    fah[mi], fbh[ni], acc[mi][ni], 0, 0, 0);
                acc[mi][ni] = __builtin_amdgcn_mfma_f32_16x16x32_f16(
                    fah[mi], fbm[ni], acc[mi][ni], 0, 0, 0);
                acc[mi][ni] = __builtin_amdgcn_mfma_f32_16x16x32_f16(
                    fam[mi], fbh[ni], acc[mi][ni], 0, 0, 0);
            }
    }

    const int orow0 = wr * 64 + (lane >> 4) * 4;
    const int ocol0 = wc * 64 + (lane & 15);
#pragma unroll
    for (int mi = 0; mi < 4; ++mi)
#pragma unroll
        for (int ni = 0; ni < 4; ++ni) {
            size_t col = bn + ocol0 + ni * 16;
            float badd = bias ? bscale * bias[col] : 0.f;
            size_t rbase = bm + orow0 + mi * 16;
#pragma unroll
            for (int r = 0; r < 4; ++r)
                C[(rbase + r) * N + col] = alpha * acc[mi][ni][r] + badd;
        }
}

// ---------------------------------------------------------------------------
template <int NR>
__device__ void wave_topk(const float* __restrict__ srow, int lane,
                          float* topv, int* topi)
{
    float vals[32];
#pragma unroll
    for (int i = 0; i < 32; ++i) vals[i] = srow[lane + (i << 6)];
#pragma unroll
    for (int r = 0; r < NR; ++r) {
        float bvv = -3.4e38f; int bii = 0x7fffffff;
#pragma unroll
        for (int i = 0; i < 32; ++i)
            if (vals[i] > bvv) { bvv = vals[i]; bii = lane + (i << 6); }
#pragma unroll
        for (int off = 32; off > 0; off >>= 1) {
            float ov = __shfl_xor(bvv, off);
            int   oi = __shfl_xor(bii, off);
            if (ov > bvv || (ov == bvv && oi < bii)) { bvv = ov; bii = oi; }
        }
        topv[r] = bvv; topi[r] = bii;
        if ((bii & 63) == lane) vals[bii >> 6] = -3.4e38f;
    }
}

// ---------------------------------------------------------------------------
__global__ __launch_bounds__(256) void select_combine(
    const float* __restrict__ scores, const float* __restrict__ v,
    float* __restrict__ retrc,
    int* __restrict__ amb_count, int* __restrict__ amb_rows)
{
    const int lane = threadIdx.x & 63;
    const int wave = threadIdx.x >> 6;
    const int row = blockIdx.x * 4 + wave;

    float topv[9]; int topi[9];
    wave_topk<9>(scores + (size_t)row * S2, lane, topv, topi);

    if ((topv[7] - topv[8]) < TAU && lane == 0) {
        int idx = atomicAdd(amb_count, 1);
        if (idx < AMB_CAP) amb_rows[idx] = row;
    }

    float m = topv[0], w[KTOP], sum = 0.f;
#pragma unroll
    for (int r = 0; r < KTOP; ++r) { w[r] = expf(topv[r] - m); sum += w[r]; }
    float inv = 1.f / sum;

    const float4* v4 = (const float4*)v;
    float4* o4 = (float4*)(retrc + (size_t)row * DD);
#pragma unroll
    for (int c = 0; c < 3; ++c) {
        int col = c * 64 + lane;
        float4 accv = {0.f, 0.f, 0.f, 0.f};
#pragma unroll
        for (int r = 0; r < KTOP; ++r) {
            float4 vv = v4[(size_t)topi[r] * (DD / 4) + col];
            float wr = w[r] * inv;
            accv.x += wr * vv.x; accv.y += wr * vv.y;
            accv.z += wr * vv.z; accv.w += wr * vv.w;
        }
        o4[col] = accv;
    }
}

// ---------------------------------------------------------------------------
// F1: q64[i][j] = f64(x_row . Wq[:,j]) + bq[j].  grid (3, AMB_CAP).
// Thread owns one j; coalesced Wq[k][j] loads; 4 independent accumulators.
// Block (0,i) wave 0 also extracts the top-16 f32 candidates.
// ---------------------------------------------------------------------------
__global__ __launch_bounds__(256) void fixup_q(
    const int* __restrict__ amb_count, const int* __restrict__ amb_rows,
    const float* __restrict__ xc, const float* __restrict__ Wq,
    const float* __restrict__ bq, const float* __restrict__ scores,
    double* __restrict__ q64buf, int* __restrict__ cand)
{
    int n = *amb_count; if (n > AMB_CAP) n = AMB_CAP;
    const int i = blockIdx.y;
    if (i >= n) return;
    const int tid = threadIdx.x;
    const int j = blockIdx.x * 256 + tid;
    const int row = amb_rows[i];

    __shared__ float xs[768];
    for (int t = tid; t < 768; t += 256) xs[t] = xc[(size_t)row * 768 + t];
    __syncthreads();

    if (blockIdx.x == 0 && tid < 64) {
        float tv[16]; int ti[16];
        wave_topk<16>(scores + (size_t)row * S2, tid, tv, ti);
        if (tid < 16) cand[i * 16 + tid] = ti[tid];
    }

    double a0 = 0.0, a1 = 0.0, a2 = 0.0, a3 = 0.0;
    const float* wp = Wq + j;
#pragma unroll 4
    for (int k = 0; k < 768; k += 4) {
        a0 = fma((double)xs[k + 0], (double)wp[(size_t)(k + 0) * 768], a0);
        a1 = fma((double)xs[k + 1], (double)wp[(size_t)(k + 1) * 768], a1);
        a2 = fma((double)xs[k + 2], (double)wp[(size_t)(k + 2) * 768], a2);
        a3 = fma((double)xs[k + 3], (double)wp[(size_t)(k + 3) * 768], a3);
    }
    q64buf[(size_t)i * 768 + j] = ((a0 + a1) + (a2 + a3)) + (double)bq[j];
}

// ---------------------------------------------------------------------------
// F2: u[i][t] = sum_j WkT[j][t] * q64[i][j].  grid (3, AMB_CAP).
// Thread owns one t; coalesced WkT loads. Block (0,i) wave 0 adds bkq.
// ---------------------------------------------------------------------------
__global__ __launch_bounds__(256) void fixup_u(
    const int* __restrict__ amb_count,
    const float* __restrict__ WkT, const float* __restrict__ bk,
    const double* __restrict__ q64buf,
    double* __restrict__ ubuf, double* __restrict__ bkqbuf)
{
    int n = *amb_count; if (n > AMB_CAP) n = AMB_CAP;
    const int i = blockIdx.y;
    if (i >= n) return;
    const int tid = threadIdx.x;
    const int t = blockIdx.x * 256 + tid;

    __shared__ double qs[768];
    const double* qrow = q64buf + (size_t)i * 768;
    for (int k = tid; k < 768; k += 256) qs[k] = qrow[k];
    __syncthreads();

    double a0 = 0.0, a1 = 0.0, a2 = 0.0, a3 = 0.0;
    const float* wp = WkT + t;
#pragma unroll 4
    for (int j = 0; j < 768; j += 4) {
        a0 = fma((double)wp[(size_t)(j + 0) * 768], qs[j + 0], a0);
        a1 = fma((double)wp[(size_t)(j + 1) * 768], qs[j + 1], a1);
        a2 = fma((double)wp[(size_t)(j + 2) * 768], qs[j + 2], a2);
        a3 = fma((double)wp[(size_t)(j + 3) * 768], qs[j + 3], a3);
    }
    ubuf[(size_t)i * 768 + t] = (a0 + a1) + (a2 + a3);

    if (blockIdx.x == 0 && tid < 64) {
        double p = 0.0;
#pragma unroll
        for (int c = 0; c < 12; ++c) {
            int j = tid + (c << 6);
            p = fma((double)bk[j], qs[j], p);
        }
#pragma unroll
        for (int off = 32; off; off >>= 1) p += __shfl_xor(p, off);
        if (tid == 0) bkqbuf[i] = p;
    }
}

// ---------------------------------------------------------------------------
// F3: per amb row: 16 exact candidate scores, f64 top-8 (val desc, idx asc),
// f64 softmax, combine v rows, overwrite retr row. grid (AMB_CAP).
// ---------------------------------------------------------------------------
__global__ __launch_bounds__(256) void fixup_sel(
    const int* __restrict__ amb_count, const int* __restrict__ amb_rows,
    const float* __restrict__ xb, const float* __restrict__ pm,
    const int* __restrict__ cand, const double* __restrict__ ubuf,
    const double* __restrict__ bkqbuf, const float* __restrict__ v,
    float* __restrict__ retrc)
{
    int n = *amb_count; if (n > AMB_CAP) n = AMB_CAP;
    const int i = blockIdx.x;
    if (i >= n) return;
    const int tid = threadIdx.x;
    const int lane = tid & 63;
    const int wave = tid >> 6;
    const int row = amb_rows[i];

    __shared__ double us[768];
    __shared__ double cs_s[16];
    __shared__ float wsm[KTOP];
    __shared__ int seli[KTOP];

    const double* urow = ubuf + (size_t)i * 768;
    for (int t = tid; t < 768; t += 256) us[t] = urow[t];
    __syncthreads();

    const double ISQ = 1.0 / sqrt((double)DD);
    const double bkq = bkqbuf[i];
#pragma unroll
    for (int c = wave; c < 16; c += 4) {
        int s = cand[i * 16 + c];
        double p = 0.0;
        if (s < SS) {
            const float* xr = xb + (size_t)(4 * s) * 768;
#pragma unroll
            for (int t = 0; t < 12; ++t) {
                int j2 = lane + (t << 6);
                double sv = 0.25 * ((double)xr[j2] + (double)xr[j2 + 768] +
                                    (double)xr[j2 + 1536] + (double)xr[j2 + 2304]);
                p = fma(sv, us[j2], p);
            }
        } else {
            const float* pr = pm + (size_t)(s - SS) * 768;
#pragma unroll
            for (int t = 0; t < 12; ++t) {
                int j2 = lane + (t << 6);
                p = fma((double)pr[j2], us[j2], p);
            }
        }
#pragma unroll
        for (int off = 32; off; off >>= 1) p += __shfl_xor(p, off);
        if (lane == 0) cs_s[c] = (p + bkq) * ISQ;
    }
    __syncthreads();

    if (tid == 0) {
        double cs[16]; int ci[16];
        for (int c = 0; c < 16; ++c) { cs[c] = cs_s[c]; ci[c] = cand[i * 16 + c]; }
        unsigned used = 0;
        double sv[KTOP]; int sx[KTOP];
        for (int r = 0; r < KTOP; ++r) {
            int bi = -1;
            for (int c = 0; c < 16; ++c) {
                if (used & (1u << c)) continue;
                if (bi < 0 || cs[c] > cs[bi] ||
                    (cs[c] == cs[bi] && ci[c] < ci[bi])) bi = c;
            }
            used |= (1u << bi); sv[r] = cs[bi]; sx[r] = ci[bi];
        }
        double mx = sv[0], es[KTOP], ssum = 0.0;
        for (int r = 0; r < KTOP; ++r) { es[r] = exp(sv[r] - mx); ssum += es[r]; }
        for (int r = 0; r < KTOP; ++r) { wsm[r] = (float)(es[r] / ssum); seli[r] = sx[r]; }
    }
    __syncthreads();
    for (int j = tid; j < 768; j += 256) {
        float o = 0.f;
#pragma unroll
        for (int r = 0; r < KTOP; ++r) o += wsm[r] * v[(size_t)seli[r] * 768 + j];
        retrc[(size_t)row * 768 + j] = o;
    }
}

// ---------------------------------------------------------------------------
extern "C" void kernel_launch(void* const* d_in, const int* in_sizes, int n_in,
                              void* d_out, int out_size, void* d_ws, size_t ws_size,
                              hipStream_t stream)
{
    const float* x  = (const float*)d_in[0];
    const float* Wq = (const float*)d_in[1];
    const float* bq = (const float*)d_in[2];
    const float* Wk = (const float*)d_in[3];
    const float* bk = (const float*)d_in[4];
    const float* Wv = (const float*)d_in[5];
    const float* bv = (const float*)d_in[6];
    const float* Wp = (const float*)d_in[7];
    const float* bp = (const float*)d_in[8];
    const float* pm = (const float*)d_in[9];
    float* out = (float*)d_out;
    float* ws  = (float*)d_ws;

    const float inv_sqrt_d = (float)(1.0 / sqrt((double)DD));
    const size_t TD  = (size_t)TT * DD;
    const size_t SD2 = (size_t)S2 * DD;
    const size_t WSZ = (size_t)DD * DD;

    float* p = ws;
    float* WqT = p; p += WSZ;
    float* WkT = p; p += WSZ;
    float* WvT = p; p += WSZ;
    float* WpT = p; p += WSZ;
    float* slots = p; p += SD2;
    float* q32 = p; p += TD;
    float* k32 = p; p += SD2;
    float* v32 = p; p += SD2;
    float* retr = p; p += TD;
    double* q64buf = (double*)p; p += (size_t)AMB_CAP * DD * 2;
    double* ubuf   = (double*)p; p += (size_t)AMB_CAP * DD * 2;
    double* bkqbuf = (double*)p; p += AMB_CAP * 2;
    int* cand = (int*)p; p += (size_t)AMB_CAP * 16;
    int* ambc = (int*)p; p += 64;
    int* ambrows = (int*)p; p += AMB_CAP;
    float* scores = p;
    size_t used = (size_t)(p - ws);

    long tc = TT;
    while (tc > 512 && (used + (size_t)tc * S2) * 4 > ws_size) tc >>= 1;

    transpose768<<<dim3(24, 24), 256, 0, stream>>>(Wq, WqT);
    transpose768<<<dim3(24, 24), 256, 0, stream>>>(Wk, WkT);
    transpose768<<<dim3(24, 24), 256, 0, stream>>>(Wv, WvT);
    transpose768<<<dim3(24, 24), 256, 0, stream>>>(Wp, WpT);

    for (int b = 0; b < BB; ++b) {
        const float* xb = x + (size_t)b * TD;
        build_slots<<<(SS * DD) / 256, 256, 0, stream>>>(xb, pm, slots);
        mfma_nt_split<<<dim3(6, 32), 256, 0, stream>>>(
            xb, WqT, bq, q32, DD, 1.f, 1.f);
        mfma_nt_split<<<dim3(6, 16), 256, 0, stream>>>(
            slots, WkT, bk, k32, DD, 1.f, 1.f);
        mfma_nt_split<<<dim3(6, 16), 256, 0, stream>>>(
            slots, WvT, bv, v32, DD, 1.f, 1.f);

        for (long t0 = 0; t0 < TT; t0 += tc) {
            zero1<<<1, 1, 0, stream>>>(ambc);
            mfma_nt_split<<<dim3(16, tc / 128), 256, 0, stream>>>(
                q32 + (size_t)t0 * DD, k32, (const float*)nullptr, scores,
                S2, inv_sqrt_d, 0.f);
            select_combine<<<tc / 4, 256, 0, stream>>>(
                scores, v32, retr + (size_t)t0 * DD, ambc, ambrows);
            fixup_q<<<dim3(3, AMB_CAP), 256, 0, stream>>>(
                ambc, ambrows, xb + (size_t)t0 * DD, Wq, bq, scores,
                q64buf, cand);
            fixup_u<<<dim3(3, AMB_CAP), 256, 0, stream>>>(
                ambc, WkT, bk, q64buf, ubuf, bkqbuf);
            fixup_sel<<<AMB_CAP, 256, 0, stream>>>(
                ambc, ambrows, xb, pm, cand, ubuf, bkqbuf, v32,
                retr + (size_t)t0 * DD);
        }

        mfma_nt_split<<<dim3(6, 32), 256, 0, stream>>>(
            retr, WpT, bp, out + (size_t)b * TD, DD, RWEIGHT, RWEIGHT);
    }
}